// Round 1
// baseline (432.135 us; speedup 1.0000x reference)
//
#include <hip/hip_runtime.h>
#include <math.h>

#define NATOM 286
#define NB2   2
#define NN    81796          /* 286*286 */
#define ECAP  82082          /* 2 * 286*287/2 : max unordered pairs incl. self */

// Softplus(beta=5): log1p(exp(5x))/5, numerically stable form
__device__ __forceinline__ float sp5(float x) {
    float z = 5.0f * x;
    return (fmaxf(z, 0.0f) + log1pf(__expf(-fabsf(z)))) * 0.2f;
}

// ---------------- init: zero edge counter + f1/f2/f3, gather f0 = emb[Z] ----
__global__ void init_kernel(const int* __restrict__ Z, const float* __restrict__ emb,
                            float* __restrict__ f0, float* __restrict__ f123,
                            int* __restrict__ cnt) {
    int idx = blockIdx.x * blockDim.x + threadIdx.x;
    int stride = gridDim.x * blockDim.x;
    if (idx == 0) cnt[0] = 0;
    for (int i = idx; i < NB2 * NATOM * 4; i += stride)
        f0[i] = emb[Z[i >> 2] * 4 + (i & 3)];
    for (int i = idx; i < NB2 * NATOM * 8 * 3; i += stride)
        f123[i] = 0.0f;
}

// ---------------- edge compaction: unordered pairs (a<=n) with dist<=3 ------
__global__ void edge_kernel(const float* __restrict__ xyz, float4* __restrict__ edges,
                            int* __restrict__ cnt) {
    int idx = blockIdx.x * blockDim.x + threadIdx.x;
    if (idx >= NB2 * NN) return;
    int b = idx / NN;
    int rem = idx - b * NN;
    int a = rem / NATOM;
    int n = rem - a * NATOM;
    if (n < a) return;                       // dist symmetric -> K symmetric
    const float* pa = xyz + (size_t)(b * NATOM + a) * 3;
    const float* pn = xyz + (size_t)(b * NATOM + n) * 3;
    float dx = pa[0] - pn[0];
    float dy = pa[1] - pn[1];
    float dz = pa[2] - pn[2];
    float d = sqrtf(dx * dx + dy * dy + dz * dz + 1e-12f);
    if (d > 3.0f) return;                    // mask==0 -> contributes nothing
    float bas[3];
    #pragma unroll
    for (int k = 0; k < 3; ++k) {
        float x = (d - 1.5f * (float)k) * (1.0f / 1.5f);
        float v = 0.0f;
        if (fabsf(x) < 1.0f) {
            float ct = cosf(1.5707963267948966f * x);
            v = ct * ct;
        }
        bas[k] = v;
    }
    int pos = atomicAdd(cnt, 1);
    edges[pos] = make_float4(__int_as_float(idx), bas[0], bas[1], bas[2]);
}

// ---------------- fused radial-MLP + scatter conv ---------------------------
// 64-edge tiles; 256 threads as 16(r: edge groups of 4) x 16(c: col groups).
// LDS ping-pong X0/X1 (64x151 fp32 each, stride 151 = conflict-free broadcast).
template <int DIN>
__global__ __launch_bounds__(256, 2)
void conv_kernel(const float* __restrict__ W1, const float* __restrict__ W2,
                 const float* __restrict__ W3, const float* __restrict__ Wo,
                 const float* __restrict__ f_in, float* __restrict__ f_out,
                 const float4* __restrict__ edges, const int* __restrict__ cnt) {
    constexpr int TOUT = 8 * DIN;            // d_out * d_in (32 or 64)
    constexpr int NCO = TOUT / 16;           // out-layer cols per thread
    const float S1 = 0.5773502691896258f;    // 1/sqrt(3)
    const float SH = 0.08164965809277261f;   // 1/sqrt(150)
    const float SD = (DIN == 4) ? 0.5f : 0.3535533905932738f; // 1/sqrt(DIN)

    __shared__ float X0[64 * 151];
    __shared__ float X1[64 * 151];
    __shared__ float basL[64 * 3];
    __shared__ int metaL[64];

    const int tid = threadIdx.x;
    const int r = tid >> 4;
    const int c = tid & 15;

    int tcol[10];
    bool tval[10];
    #pragma unroll
    for (int i = 0; i < 10; ++i) {
        int t = c + 16 * i;
        tval[i] = (t < 150);
        tcol[i] = tval[i] ? t : 0;           // clamp: harmless in-bounds load
    }

    const int E = cnt[0];
    const int ntile = (E + 63) >> 6;

    for (int tile = blockIdx.x; tile < ntile; tile += gridDim.x) {
        const int base = tile << 6;
        if (tid < 64) {
            int ei = base + tid;
            if (ei < E) {
                float4 v = edges[ei];
                metaL[tid] = __float_as_int(v.x);
                basL[tid * 3 + 0] = v.y;
                basL[tid * 3 + 1] = v.z;
                basL[tid * 3 + 2] = v.w;
            } else {
                metaL[tid] = -1;
                basL[tid * 3 + 0] = 0.0f;
                basL[tid * 3 + 1] = 0.0f;
                basL[tid * 3 + 2] = 0.0f;
            }
        }
        __syncthreads();

        // ---- layer 1: basis(3) @ W1 -> X0
        #pragma unroll
        for (int j = 0; j < 4; ++j) {
            int e = 4 * r + j;
            float b0 = basL[e * 3 + 0];
            float b1 = basL[e * 3 + 1];
            float b2 = basL[e * 3 + 2];
            #pragma unroll
            for (int i = 0; i < 10; ++i) {
                float acc = b0 * W1[tcol[i]] + b1 * W1[150 + tcol[i]] + b2 * W1[300 + tcol[i]];
                if (tval[i]) X0[e * 151 + tcol[i]] = sp5(acc * S1);
            }
        }
        __syncthreads();

        // ---- layer 2: X0 @ W2 -> X1
        {
            float acc[4][10];
            #pragma unroll
            for (int j = 0; j < 4; ++j)
                #pragma unroll
                for (int i = 0; i < 10; ++i) acc[j][i] = 0.0f;
            #pragma unroll 2
            for (int k = 0; k < 150; ++k) {
                float x0 = X0[(4 * r + 0) * 151 + k];
                float x1 = X0[(4 * r + 1) * 151 + k];
                float x2 = X0[(4 * r + 2) * 151 + k];
                float x3 = X0[(4 * r + 3) * 151 + k];
                const float* wrow = W2 + k * 150;
                #pragma unroll
                for (int i = 0; i < 10; ++i) {
                    float w = wrow[tcol[i]];
                    acc[0][i] += x0 * w;
                    acc[1][i] += x1 * w;
                    acc[2][i] += x2 * w;
                    acc[3][i] += x3 * w;
                }
            }
            #pragma unroll
            for (int j = 0; j < 4; ++j)
                #pragma unroll
                for (int i = 0; i < 10; ++i)
                    if (tval[i]) X1[(4 * r + j) * 151 + tcol[i]] = sp5(acc[j][i] * SH);
        }
        __syncthreads();

        // ---- layer 3: X1 @ W3 -> X0
        {
            float acc[4][10];
            #pragma unroll
            for (int j = 0; j < 4; ++j)
                #pragma unroll
                for (int i = 0; i < 10; ++i) acc[j][i] = 0.0f;
            #pragma unroll 2
            for (int k = 0; k < 150; ++k) {
                float x0 = X1[(4 * r + 0) * 151 + k];
                float x1 = X1[(4 * r + 1) * 151 + k];
                float x2 = X1[(4 * r + 2) * 151 + k];
                float x3 = X1[(4 * r + 3) * 151 + k];
                const float* wrow = W3 + k * 150;
                #pragma unroll
                for (int i = 0; i < 10; ++i) {
                    float w = wrow[tcol[i]];
                    acc[0][i] += x0 * w;
                    acc[1][i] += x1 * w;
                    acc[2][i] += x2 * w;
                    acc[3][i] += x3 * w;
                }
            }
            #pragma unroll
            for (int j = 0; j < 4; ++j)
                #pragma unroll
                for (int i = 0; i < 10; ++i)
                    if (tval[i]) X0[(4 * r + j) * 151 + tcol[i]] = sp5(acc[j][i] * SH);
        }
        __syncthreads();

        // ---- output layer: X0 @ Wo -> Wout (stored in X1 area, stride 65)
        {
            float acc[4][NCO];
            #pragma unroll
            for (int j = 0; j < 4; ++j)
                #pragma unroll
                for (int i = 0; i < NCO; ++i) acc[j][i] = 0.0f;
            #pragma unroll 2
            for (int k = 0; k < 150; ++k) {
                float x0 = X0[(4 * r + 0) * 151 + k];
                float x1 = X0[(4 * r + 1) * 151 + k];
                float x2 = X0[(4 * r + 2) * 151 + k];
                float x3 = X0[(4 * r + 3) * 151 + k];
                const float* wrow = Wo + k * TOUT;
                #pragma unroll
                for (int i = 0; i < NCO; ++i) {
                    float w = wrow[c + 16 * i];
                    acc[0][i] += x0 * w;
                    acc[1][i] += x1 * w;
                    acc[2][i] += x2 * w;
                    acc[3][i] += x3 * w;
                }
            }
            #pragma unroll
            for (int j = 0; j < 4; ++j)
                #pragma unroll
                for (int i = 0; i < NCO; ++i)
                    X1[(4 * r + j) * 65 + c + 16 * i] = acc[j][i] * SH;
        }
        __syncthreads();

        // ---- scatter: out[b,a,i] += K.f[b,n];  out[b,n,i] += K.f[b,a]
        #pragma unroll
        for (int p = 0; p < 2; ++p) {
            int e = p * 32 + (tid >> 3);
            int i = tid & 7;
            int meta = metaL[e];
            if (meta >= 0) {
                int b = meta / NN;
                int rm = meta - b * NN;
                int a = rm / NATOM;
                int n = rm - a * NATOM;
                const float* krow = &X1[e * 65 + i * DIN];
                const float* fn = f_in + (size_t)(b * NATOM + n) * DIN;
                float dot = 0.0f;
                #pragma unroll
                for (int jj = 0; jj < DIN; ++jj) dot += krow[jj] * fn[jj];
                atomicAdd(&f_out[(size_t)(b * NATOM + a) * 8 + i], dot * SD);
                if (n != a) {
                    const float* fa = f_in + (size_t)(b * NATOM + a) * DIN;
                    float dot2 = 0.0f;
                    #pragma unroll
                    for (int jj = 0; jj < DIN; ++jj) dot2 += krow[jj] * fa[jj];
                    atomicAdd(&f_out[(size_t)(b * NATOM + n) * 8 + i], dot2 * SD);
                }
            }
        }
        __syncthreads();
    }
}

// ---------------- epilogue: lp_pool + linear + BN(batch of 2) + LeakyReLU ---
__global__ void epilogue_kernel(const float* __restrict__ f1, const float* __restrict__ f2,
                                const float* __restrict__ f3,
                                const float* __restrict__ lin_w, const float* __restrict__ lin_b,
                                const float* __restrict__ bn_g, const float* __restrict__ bn_b,
                                float* __restrict__ out) {
    __shared__ float pooled[48];
    __shared__ float yv[48];
    int tid = threadIdx.x;
    if (tid < 48) {
        int b = tid / 24, ch = tid % 24;
        const float* src = (ch < 8)  ? (f1 + (size_t)(b * NATOM) * 8 + ch)
                         : (ch < 16) ? (f2 + (size_t)(b * NATOM) * 8 + (ch - 8))
                                     : (f3 + (size_t)(b * NATOM) * 8 + (ch - 16));
        float s = 0.0f;
        for (int n = 0; n < NATOM; ++n) { float v = src[(size_t)n * 8]; s += v * v; }
        pooled[tid] = sqrtf(s + 1e-12f);
    }
    __syncthreads();
    if (tid < 48) {
        int b = tid / 24, o = tid % 24;
        float y = lin_b[o];
        for (int cc = 0; cc < 24; ++cc) y += pooled[b * 24 + cc] * lin_w[o * 24 + cc];
        yv[b * 24 + o] = y;
    }
    __syncthreads();
    if (tid < 24) {
        int o = tid;
        float y0 = yv[o], y1 = yv[24 + o];
        float m = 0.5f * (y0 + y1);
        float v = 0.5f * ((y0 - m) * (y0 - m) + (y1 - m) * (y1 - m));
        float inv = rsqrtf(v + 1e-5f);
        float g = bn_g[o], bb = bn_b[o];
        float t0 = (y0 - m) * inv * g + bb;
        float t1 = (y1 - m) * inv * g + bb;
        out[o]      = t0 > 0.0f ? t0 : 0.2f * t0;
        out[24 + o] = t1 > 0.0f ? t1 : 0.2f * t1;
    }
}

extern "C" void kernel_launch(void* const* d_in, const int* in_sizes, int n_in,
                              void* d_out, int out_size, void* d_ws, size_t ws_size,
                              hipStream_t stream) {
    const float* xyz  = (const float*)d_in[0];
    const int*   Z    = (const int*)d_in[1];
    const float* emb  = (const float*)d_in[2];
    const float* c0w1 = (const float*)d_in[3];
    const float* c0w2 = (const float*)d_in[4];
    const float* c0w3 = (const float*)d_in[5];
    const float* c0wo = (const float*)d_in[6];
    const float* c1w1 = (const float*)d_in[7];
    const float* c1w2 = (const float*)d_in[8];
    const float* c1w3 = (const float*)d_in[9];
    const float* c1wo = (const float*)d_in[10];
    const float* c2w1 = (const float*)d_in[11];
    const float* c2w2 = (const float*)d_in[12];
    const float* c2w3 = (const float*)d_in[13];
    const float* c2wo = (const float*)d_in[14];
    const float* linw = (const float*)d_in[15];
    const float* linb = (const float*)d_in[16];
    const float* bng  = (const float*)d_in[17];
    const float* bnb  = (const float*)d_in[18];
    float* outp = (float*)d_out;

    // workspace layout: [cnt(16B)][edges ECAP*16B][f0][f1][f2][f3]  (~1.4 MB)
    char* ws = (char*)d_ws;
    int* cnt = (int*)ws;
    float4* edges = (float4*)(ws + 16);
    float* f0 = (float*)(ws + 16 + (size_t)ECAP * 16);
    float* f1 = f0 + NB2 * NATOM * 4;
    float* f2 = f1 + NB2 * NATOM * 8;
    float* f3 = f2 + NB2 * NATOM * 8;

    init_kernel<<<32, 256, 0, stream>>>(Z, emb, f0, f1, cnt);
    edge_kernel<<<(NB2 * NN + 255) / 256, 256, 0, stream>>>(xyz, edges, cnt);
    conv_kernel<4><<<160, 256, 0, stream>>>(c0w1, c0w2, c0w3, c0wo, f0, f1, edges, cnt);
    conv_kernel<8><<<160, 256, 0, stream>>>(c1w1, c1w2, c1w3, c1wo, f1, f2, edges, cnt);
    conv_kernel<8><<<160, 256, 0, stream>>>(c2w1, c2w2, c2w3, c2wo, f2, f3, edges, cnt);
    epilogue_kernel<<<1, 64, 0, stream>>>(f1, f2, f3, linw, linb, bng, bnb, outp);
}

// Round 2
// 239.261 us; speedup vs baseline: 1.8061x; 1.8061x over previous
//
#include <hip/hip_runtime.h>
#include <math.h>

#define NATOM 286
#define NB2   2
#define NN    81796          /* 286*286 */
#define ECAP  82082          /* 2 * 286*287/2 : max unordered pairs incl. self */

// Softplus(beta=5): log1p(exp(5x))/5, numerically stable form
__device__ __forceinline__ float sp5(float x) {
    float z = 5.0f * x;
    return (fmaxf(z, 0.0f) + log1pf(__expf(-fabsf(z)))) * 0.2f;
}

// ---------------- init: zero edge counter + f1/f2/f3, gather f0 = emb[Z] ----
__global__ void init_kernel(const int* __restrict__ Z, const float* __restrict__ emb,
                            float* __restrict__ f0, float* __restrict__ f123,
                            int* __restrict__ cnt) {
    int idx = blockIdx.x * blockDim.x + threadIdx.x;
    int stride = gridDim.x * blockDim.x;
    if (idx == 0) cnt[0] = 0;
    for (int i = idx; i < NB2 * NATOM * 4; i += stride)
        f0[i] = emb[Z[i >> 2] * 4 + (i & 3)];
    for (int i = idx; i < NB2 * NATOM * 8 * 3; i += stride)
        f123[i] = 0.0f;
}

// ---------------- edge compaction: unordered pairs (a<=n) with dist<=3 ------
__global__ void edge_kernel(const float* __restrict__ xyz, float4* __restrict__ edges,
                            int* __restrict__ cnt) {
    int idx = blockIdx.x * blockDim.x + threadIdx.x;
    if (idx >= NB2 * NN) return;
    int b = idx / NN;
    int rem = idx - b * NN;
    int a = rem / NATOM;
    int n = rem - a * NATOM;
    if (n < a) return;                       // dist symmetric -> K symmetric
    const float* pa = xyz + (size_t)(b * NATOM + a) * 3;
    const float* pn = xyz + (size_t)(b * NATOM + n) * 3;
    float dx = pa[0] - pn[0];
    float dy = pa[1] - pn[1];
    float dz = pa[2] - pn[2];
    float d = sqrtf(dx * dx + dy * dy + dz * dz + 1e-12f);
    if (d > 3.0f) return;                    // mask==0 -> contributes nothing
    float bas[3];
    #pragma unroll
    for (int k = 0; k < 3; ++k) {
        float x = (d - 1.5f * (float)k) * (1.0f / 1.5f);
        float v = 0.0f;
        if (fabsf(x) < 1.0f) {
            float ct = cosf(1.5707963267948966f * x);
            v = ct * ct;
        }
        bas[k] = v;
    }
    int pos = atomicAdd(cnt, 1);
    edges[pos] = make_float4(__int_as_float(idx), bas[0], bas[1], bas[2]);
}

// ---------------- fused radial MLP for ALL THREE convs ----------------------
// All radial MLPs depend only on dist -> independent -> one launch, 3x blocks.
// 32-edge tiles; 256 threads = 8 r-groups (4 edges each) x 32 c-lanes (5 cols).
// LDS: 2 x 32x151 fp32 = 38.7 KB -> 4 blocks/CU; expected ~10 waves/CU.
__global__ __launch_bounds__(256, 4)
void radial_kernel(const float* __restrict__ W1_0, const float* __restrict__ W2_0,
                   const float* __restrict__ W3_0, const float* __restrict__ Wo_0,
                   const float* __restrict__ W1_1, const float* __restrict__ W2_1,
                   const float* __restrict__ W3_1, const float* __restrict__ Wo_1,
                   const float* __restrict__ W1_2, const float* __restrict__ W2_2,
                   const float* __restrict__ W3_2, const float* __restrict__ Wo_2,
                   float* __restrict__ Kbuf,
                   const float4* __restrict__ edges, const int* __restrict__ cnt) {
    const float S1 = 0.5773502691896258f;    // 1/sqrt(3)
    const float SH = 0.08164965809277261f;   // 1/sqrt(150)

    __shared__ float X0[32 * 151];
    __shared__ float X1[32 * 151];

    const int tid = threadIdx.x;
    const int r = tid >> 5;                  // 0..7, owns edges 4r..4r+3
    const int c = tid & 31;                  // col lane

    int tcol[5];
    bool tval[5];
    #pragma unroll
    for (int i = 0; i < 5; ++i) {
        int t = c + 32 * i;
        tval[i] = (t < 150);
        tcol[i] = tval[i] ? t : 0;
    }

    const int E = cnt[0];
    const int ntile = (E + 31) >> 5;
    const int items = 3 * ntile;

    for (int item = blockIdx.x; item < items; item += gridDim.x) {
        const int conv = (item < ntile) ? 0 : ((item < 2 * ntile) ? 1 : 2);
        const int tile = item - conv * ntile;
        const int base = tile << 5;
        const float *W1, *W2, *W3, *Wo;
        int TOUT;
        if (conv == 0)      { W1 = W1_0; W2 = W2_0; W3 = W3_0; Wo = Wo_0; TOUT = 32; }
        else if (conv == 1) { W1 = W1_1; W2 = W2_1; W3 = W3_1; Wo = Wo_1; TOUT = 64; }
        else                { W1 = W1_2; W2 = W2_2; W3 = W3_2; Wo = Wo_2; TOUT = 64; }

        __syncthreads();     // protect X0 against previous item's output reads

        // ---- layer 1: basis(3) @ W1 -> X0
        #pragma unroll
        for (int j = 0; j < 4; ++j) {
            int e = 4 * r + j;
            int ge = base + e;
            float b0 = 0.0f, b1 = 0.0f, b2 = 0.0f;
            if (ge < E) {
                float4 v = edges[ge];
                b0 = v.y; b1 = v.z; b2 = v.w;
            }
            #pragma unroll
            for (int i = 0; i < 5; ++i) {
                float acc = b0 * W1[tcol[i]] + b1 * W1[150 + tcol[i]] + b2 * W1[300 + tcol[i]];
                if (tval[i]) X0[e * 151 + tcol[i]] = sp5(acc * S1);
            }
        }
        __syncthreads();

        // ---- layer 2: X0 @ W2 -> X1
        {
            float acc[4][5];
            #pragma unroll
            for (int j = 0; j < 4; ++j)
                #pragma unroll
                for (int i = 0; i < 5; ++i) acc[j][i] = 0.0f;
            #pragma unroll 2
            for (int k = 0; k < 150; ++k) {
                float x0 = X0[(4 * r + 0) * 151 + k];
                float x1 = X0[(4 * r + 1) * 151 + k];
                float x2 = X0[(4 * r + 2) * 151 + k];
                float x3 = X0[(4 * r + 3) * 151 + k];
                const float* wrow = W2 + k * 150;
                #pragma unroll
                for (int i = 0; i < 5; ++i) {
                    float w = wrow[tcol[i]];
                    acc[0][i] += x0 * w;
                    acc[1][i] += x1 * w;
                    acc[2][i] += x2 * w;
                    acc[3][i] += x3 * w;
                }
            }
            #pragma unroll
            for (int j = 0; j < 4; ++j)
                #pragma unroll
                for (int i = 0; i < 5; ++i)
                    if (tval[i]) X1[(4 * r + j) * 151 + tcol[i]] = sp5(acc[j][i] * SH);
        }
        __syncthreads();

        // ---- layer 3: X1 @ W3 -> X0
        {
            float acc[4][5];
            #pragma unroll
            for (int j = 0; j < 4; ++j)
                #pragma unroll
                for (int i = 0; i < 5; ++i) acc[j][i] = 0.0f;
            #pragma unroll 2
            for (int k = 0; k < 150; ++k) {
                float x0 = X1[(4 * r + 0) * 151 + k];
                float x1 = X1[(4 * r + 1) * 151 + k];
                float x2 = X1[(4 * r + 2) * 151 + k];
                float x3 = X1[(4 * r + 3) * 151 + k];
                const float* wrow = W3 + k * 150;
                #pragma unroll
                for (int i = 0; i < 5; ++i) {
                    float w = wrow[tcol[i]];
                    acc[0][i] += x0 * w;
                    acc[1][i] += x1 * w;
                    acc[2][i] += x2 * w;
                    acc[3][i] += x3 * w;
                }
            }
            #pragma unroll
            for (int j = 0; j < 4; ++j)
                #pragma unroll
                for (int i = 0; i < 5; ++i)
                    if (tval[i]) X0[(4 * r + j) * 151 + tcol[i]] = sp5(acc[j][i] * SH);
        }
        __syncthreads();

        // ---- output layer: X0 @ Wo -> Kbuf (global, uniform stride 64)
        float* Kc = Kbuf + (size_t)conv * ECAP * 64;
        if (TOUT == 64) {
            float acc[4][2];
            #pragma unroll
            for (int j = 0; j < 4; ++j) { acc[j][0] = 0.0f; acc[j][1] = 0.0f; }
            #pragma unroll 2
            for (int k = 0; k < 150; ++k) {
                float x0 = X0[(4 * r + 0) * 151 + k];
                float x1 = X0[(4 * r + 1) * 151 + k];
                float x2 = X0[(4 * r + 2) * 151 + k];
                float x3 = X0[(4 * r + 3) * 151 + k];
                const float* wrow = Wo + k * 64;
                float wa = wrow[c];
                float wb = wrow[c + 32];
                acc[0][0] += x0 * wa; acc[0][1] += x0 * wb;
                acc[1][0] += x1 * wa; acc[1][1] += x1 * wb;
                acc[2][0] += x2 * wa; acc[2][1] += x2 * wb;
                acc[3][0] += x3 * wa; acc[3][1] += x3 * wb;
            }
            #pragma unroll
            for (int j = 0; j < 4; ++j) {
                size_t row = (size_t)(base + 4 * r + j) * 64;
                Kc[row + c]      = acc[j][0] * SH;
                Kc[row + c + 32] = acc[j][1] * SH;
            }
        } else {
            float acc[4];
            #pragma unroll
            for (int j = 0; j < 4; ++j) acc[j] = 0.0f;
            #pragma unroll 2
            for (int k = 0; k < 150; ++k) {
                float x0 = X0[(4 * r + 0) * 151 + k];
                float x1 = X0[(4 * r + 1) * 151 + k];
                float x2 = X0[(4 * r + 2) * 151 + k];
                float x3 = X0[(4 * r + 3) * 151 + k];
                float wa = Wo[k * 32 + c];
                acc[0] += x0 * wa;
                acc[1] += x1 * wa;
                acc[2] += x2 * wa;
                acc[3] += x3 * wa;
            }
            #pragma unroll
            for (int j = 0; j < 4; ++j)
                Kc[(size_t)(base + 4 * r + j) * 64 + c] = acc[j] * SH;
        }
    }
}

// ---------------- scatter: f_out[a] += K.f[n]; f_out[n] += K.f[a] -----------
template <int DIN>
__global__ void scatter_kernel(const float* __restrict__ Kc, const float* __restrict__ f_in,
                               float* __restrict__ f_out, const float4* __restrict__ edges,
                               const int* __restrict__ cnt) {
    const float SD = (DIN == 4) ? 0.5f : 0.3535533905932738f;  // 1/sqrt(DIN)
    const int E = cnt[0];
    const int total = E * 8;
    for (int idx = blockIdx.x * blockDim.x + threadIdx.x; idx < total;
         idx += gridDim.x * blockDim.x) {
        int e = idx >> 3;
        int i = idx & 7;
        int meta = __float_as_int(edges[e].x);
        int b = meta / NN;
        int rm = meta - b * NN;
        int a = rm / NATOM;
        int n = rm - a * NATOM;
        const float* krow = Kc + (size_t)e * 64 + i * DIN;
        const float* fn = f_in + (size_t)(b * NATOM + n) * DIN;
        float dot = 0.0f;
        #pragma unroll
        for (int jj = 0; jj < DIN; ++jj) dot += krow[jj] * fn[jj];
        atomicAdd(&f_out[(size_t)(b * NATOM + a) * 8 + i], dot * SD);
        if (n != a) {
            const float* fa = f_in + (size_t)(b * NATOM + a) * DIN;
            float dot2 = 0.0f;
            #pragma unroll
            for (int jj = 0; jj < DIN; ++jj) dot2 += krow[jj] * fa[jj];
            atomicAdd(&f_out[(size_t)(b * NATOM + n) * 8 + i], dot2 * SD);
        }
    }
}

// ---------------- epilogue: lp_pool + linear + BN(batch of 2) + LeakyReLU ---
__global__ void epilogue_kernel(const float* __restrict__ f1, const float* __restrict__ f2,
                                const float* __restrict__ f3,
                                const float* __restrict__ lin_w, const float* __restrict__ lin_b,
                                const float* __restrict__ bn_g, const float* __restrict__ bn_b,
                                float* __restrict__ out) {
    __shared__ float pooled[48];
    __shared__ float yv[48];
    int tid = threadIdx.x;
    if (tid < 48) {
        int b = tid / 24, ch = tid % 24;
        const float* src = (ch < 8)  ? (f1 + (size_t)(b * NATOM) * 8 + ch)
                         : (ch < 16) ? (f2 + (size_t)(b * NATOM) * 8 + (ch - 8))
                                     : (f3 + (size_t)(b * NATOM) * 8 + (ch - 16));
        float s = 0.0f;
        for (int n = 0; n < NATOM; ++n) { float v = src[(size_t)n * 8]; s += v * v; }
        pooled[tid] = sqrtf(s + 1e-12f);
    }
    __syncthreads();
    if (tid < 48) {
        int b = tid / 24, o = tid % 24;
        float y = lin_b[o];
        for (int cc = 0; cc < 24; ++cc) y += pooled[b * 24 + cc] * lin_w[o * 24 + cc];
        yv[b * 24 + o] = y;
    }
    __syncthreads();
    if (tid < 24) {
        int o = tid;
        float y0 = yv[o], y1 = yv[24 + o];
        float m = 0.5f * (y0 + y1);
        float v = 0.5f * ((y0 - m) * (y0 - m) + (y1 - m) * (y1 - m));
        float inv = rsqrtf(v + 1e-5f);
        float g = bn_g[o], bb = bn_b[o];
        float t0 = (y0 - m) * inv * g + bb;
        float t1 = (y1 - m) * inv * g + bb;
        out[o]      = t0 > 0.0f ? t0 : 0.2f * t0;
        out[24 + o] = t1 > 0.0f ? t1 : 0.2f * t1;
    }
}

extern "C" void kernel_launch(void* const* d_in, const int* in_sizes, int n_in,
                              void* d_out, int out_size, void* d_ws, size_t ws_size,
                              hipStream_t stream) {
    const float* xyz  = (const float*)d_in[0];
    const int*   Z    = (const int*)d_in[1];
    const float* emb  = (const float*)d_in[2];
    const float* c0w1 = (const float*)d_in[3];
    const float* c0w2 = (const float*)d_in[4];
    const float* c0w3 = (const float*)d_in[5];
    const float* c0wo = (const float*)d_in[6];
    const float* c1w1 = (const float*)d_in[7];
    const float* c1w2 = (const float*)d_in[8];
    const float* c1w3 = (const float*)d_in[9];
    const float* c1wo = (const float*)d_in[10];
    const float* c2w1 = (const float*)d_in[11];
    const float* c2w2 = (const float*)d_in[12];
    const float* c2w3 = (const float*)d_in[13];
    const float* c2wo = (const float*)d_in[14];
    const float* linw = (const float*)d_in[15];
    const float* linb = (const float*)d_in[16];
    const float* bng  = (const float*)d_in[17];
    const float* bnb  = (const float*)d_in[18];
    float* outp = (float*)d_out;

    // ws layout: [cnt 16B][edges ECAP*16B][f0][f1][f2][f3][K: 3*ECAP*64*4B]
    char* ws = (char*)d_ws;
    int* cnt = (int*)ws;
    float4* edges = (float4*)(ws + 16);
    float* f0 = (float*)(ws + 16 + (size_t)ECAP * 16);
    float* f1 = f0 + NB2 * NATOM * 4;
    float* f2 = f1 + NB2 * NATOM * 8;
    float* f3 = f2 + NB2 * NATOM * 8;
    size_t koff = (size_t)(16 + (size_t)ECAP * 16 + (NB2 * NATOM * (4 + 8 * 3)) * 4);
    koff = (koff + 255) & ~(size_t)255;
    float* Kbuf = (float*)(ws + koff);       // 3 * ECAP * 64 floats = 63 MB

    init_kernel<<<32, 256, 0, stream>>>(Z, emb, f0, f1, cnt);
    edge_kernel<<<(NB2 * NN + 255) / 256, 256, 0, stream>>>(xyz, edges, cnt);
    radial_kernel<<<1024, 256, 0, stream>>>(c0w1, c0w2, c0w3, c0wo,
                                            c1w1, c1w2, c1w3, c1wo,
                                            c2w1, c2w2, c2w3, c2wo,
                                            Kbuf, edges, cnt);
    scatter_kernel<4><<<64, 256, 0, stream>>>(Kbuf,                          f0, f1, edges, cnt);
    scatter_kernel<8><<<64, 256, 0, stream>>>(Kbuf + (size_t)ECAP * 64,      f1, f2, edges, cnt);
    scatter_kernel<8><<<64, 256, 0, stream>>>(Kbuf + (size_t)ECAP * 128,     f2, f3, edges, cnt);
    epilogue_kernel<<<1, 64, 0, stream>>>(f1, f2, f3, linw, linb, bng, bnb, outp);
}

// Round 3
// 161.726 us; speedup vs baseline: 2.6720x; 1.4794x over previous
//
#include <hip/hip_runtime.h>
#include <math.h>

#define NATOM 286
#define NB2   2
#define NN    81796          /* 286*286 */
#define ECAP  82082          /* 2 * 286*287/2 : max unordered pairs incl. self */
#define PW_STRIDE 61440      /* u16 per conv: W2 25600 + W3 25600 + Wo 10240 */
#define PW_OUT_OFF 51200

typedef unsigned short u16;
typedef unsigned int   u32;

using bf16x8 = __attribute__((ext_vector_type(8))) short;
using f32x4  = __attribute__((ext_vector_type(4))) float;

// Softplus(beta=5), stable: (max(z,0) + log(1+exp(-|z|)))/5
__device__ __forceinline__ float sp5(float x) {
    float z = 5.0f * x;
    return (fmaxf(z, 0.0f) + __logf(1.0f + __expf(-fabsf(z)))) * 0.2f;
}
__device__ __forceinline__ u16 f2bf(float x) {           // RTNE fp32->bf16
    union { float f; u32 u; } v; v.f = x;
    return (u16)((v.u + 0x7FFFu + ((v.u >> 16) & 1u)) >> 16);
}
__device__ __forceinline__ float bf2f(u16 u) {
    union { u32 u; float f; } v; v.u = ((u32)u) << 16;
    return v.f;
}

// ---------------- prep: cnt=0, f0=emb[Z], zero f1..f3, pack weights --------
// Packed B-fragment layout (per 16x16x32 mfma): dst[((nt*5+k0)*64+lane)*8+j]
//   = W[k = k0*32 + (lane>>4)*8 + j][n = nt*16 + (lane&15)] * scale  (0 pad)
__global__ void prep_kernel(const int* __restrict__ Z, const float* __restrict__ emb,
                            const float* w2a, const float* w3a, const float* woa,
                            const float* w2b, const float* w3b, const float* wob,
                            const float* w2c, const float* w3c, const float* woc,
                            float* __restrict__ f0, float* __restrict__ f123,
                            int* __restrict__ cnt, u16* __restrict__ PW) {
    int idx = blockIdx.x * blockDim.x + threadIdx.x;
    int stride = gridDim.x * blockDim.x;
    if (idx == 0) cnt[0] = 0;
    for (int i = idx; i < NB2 * NATOM * 4; i += stride)
        f0[i] = emb[Z[i >> 2] * 4 + (i & 3)];
    for (int i = idx; i < NB2 * NATOM * 8 * 3; i += stride)
        f123[i] = 0.0f;

    const float SH = 0.08164965809277261f;   // 1/sqrt(150)
    const float* W2s[3] = {w2a, w2b, w2c};
    const float* W3s[3] = {w3a, w3b, w3c};
    const float* Wos[3] = {woa, wob, woc};
    const int   TOUTs[3] = {32, 64, 64};
    const float SDs[3]  = {0.5f, 0.3535533905932738f, 0.3535533905932738f};

    for (int c = 0; c < 3; ++c) {
        u16* base = PW + c * PW_STRIDE;
        for (int which = 0; which < 2; ++which) {       // W2, W3 (150x150)
            const float* src = which ? W3s[c] : W2s[c];
            u16* dst = base + which * 25600;
            for (int d = idx; d < 25600; d += stride) {
                int j = d & 7, lane = (d >> 3) & 63, rest = d >> 9;
                int k0 = rest % 5, nt = rest / 5;
                int n = nt * 16 + (lane & 15);
                int k = k0 * 32 + (lane >> 4) * 8 + j;
                float v = (k < 150 && n < 150) ? src[k * 150 + n] * SH : 0.0f;
                dst[d] = f2bf(v);
            }
        }
        const float* src = Wos[c];                      // Wo (150 x TOUT)
        const int TOUT = TOUTs[c];
        const float sc = SH * SDs[c];                   // fold 1/sqrt(d_in) too
        u16* dst = base + PW_OUT_OFF;
        const int tot = (TOUT / 16) * 5 * 512;
        for (int d = idx; d < tot; d += stride) {
            int j = d & 7, lane = (d >> 3) & 63, rest = d >> 9;
            int k0 = rest % 5, nt = rest / 5;
            int n = nt * 16 + (lane & 15);
            int k = k0 * 32 + (lane >> 4) * 8 + j;
            float v = (k < 150) ? src[k * TOUT + n] * sc : 0.0f;
            dst[d] = f2bf(v);
        }
    }
}

// ---------------- edge compaction: unordered pairs (a<=n) with dist<=3 ------
__global__ void edge_kernel(const float* __restrict__ xyz, float4* __restrict__ edges,
                            int* __restrict__ cnt) {
    int idx = blockIdx.x * blockDim.x + threadIdx.x;
    if (idx >= NB2 * NN) return;
    int b = idx / NN;
    int rem = idx - b * NN;
    int a = rem / NATOM;
    int n = rem - a * NATOM;
    if (n < a) return;
    const float* pa = xyz + (size_t)(b * NATOM + a) * 3;
    const float* pn = xyz + (size_t)(b * NATOM + n) * 3;
    float dx = pa[0] - pn[0];
    float dy = pa[1] - pn[1];
    float dz = pa[2] - pn[2];
    float d = sqrtf(dx * dx + dy * dy + dz * dz + 1e-12f);
    if (d > 3.0f) return;
    float bas[3];
    #pragma unroll
    for (int k = 0; k < 3; ++k) {
        float x = (d - 1.5f * (float)k) * (1.0f / 1.5f);
        float v = 0.0f;
        if (fabsf(x) < 1.0f) {
            float ct = cosf(1.5707963267948966f * x);
            v = ct * ct;
        }
        bas[k] = v;
    }
    int pos = atomicAdd(cnt, 1);
    edges[pos] = make_float4(__int_as_float(idx), bas[0], bas[1], bas[2]);
}

// ---------------- MFMA helpers ---------------------------------------------
// A frag (X[m][k], row stride 168 u16): lane holds X[m=lane&15][k0*32+(lane>>4)*8+j]
__device__ __forceinline__ void load_a(bf16x8 a[5], const u16* X, int m_off, int lane) {
    const int arow = (m_off + (lane & 15)) * 168 + (lane >> 4) * 8;
    #pragma unroll
    for (int k0 = 0; k0 < 5; ++k0)
        a[k0] = *(const bf16x8*)(X + arow + k0 * 32);
}
__device__ __forceinline__ f32x4 mfma_nt(const bf16x8 a[5], const u16* __restrict__ Bp,
                                         int nt, int lane) {
    f32x4 acc = {0.0f, 0.0f, 0.0f, 0.0f};
    #pragma unroll
    for (int k0 = 0; k0 < 5; ++k0) {
        bf16x8 b = *(const bf16x8*)(Bp + ((nt * 5 + k0) * 64 + lane) * 8);
        acc = __builtin_amdgcn_mfma_f32_16x16x32_bf16(a[k0], b, acc, 0, 0, 0);
    }
    return acc;
}
// one hidden layer: Y = sp5(X @ Wp)   (scale folded into Wp)
__device__ __forceinline__ void mfma_layer(const u16* X, u16* Y,
                                           const u16* __restrict__ Bp,
                                           int m_off, int nh, int lane) {
    bf16x8 a[5];
    load_a(a, X, m_off, lane);
    const int quad = lane >> 4;
    const int n_lane = lane & 15;
    #pragma unroll
    for (int i = 0; i < 5; ++i) {
        int nt = nh * 5 + i;
        f32x4 acc = mfma_nt(a, Bp, nt, lane);
        // C/D: col = lane&15, row = quad*4 + r   [measured m89/m91]
        int wb = (m_off + quad * 4) * 168 + nt * 16 + n_lane;
        #pragma unroll
        for (int r = 0; r < 4; ++r)
            Y[wb + r * 168] = f2bf(sp5(acc[r]));
    }
}

// ---------------- radial MLP (MFMA) for all 3 convs + fused conv0 scatter ---
// 32-edge tiles; 256 threads = 4 waves = (m-half 0/1) x (n-half 0/1).
__global__ __launch_bounds__(256, 2)
void radial_kernel(const float* __restrict__ W1_0, const float* __restrict__ W1_1,
                   const float* __restrict__ W1_2, const u16* __restrict__ PW,
                   const float* __restrict__ f0, float* __restrict__ f1,
                   u16* __restrict__ Kc1, u16* __restrict__ Kc2,
                   const float4* __restrict__ edges, const int* __restrict__ cnt) {
    __shared__ __align__(16) u16 XA[32 * 168];
    __shared__ __align__(16) u16 XB[32 * 168];
    __shared__ float basL[32][3];
    __shared__ int metaL[32];

    const int tid = threadIdx.x;
    const int lane = tid & 63;
    const int wv = tid >> 6;
    const int m_off = (wv & 1) * 16;
    const int nh = wv >> 1;
    const int n_lane = lane & 15;
    const int quad = lane >> 4;
    const float S1 = 0.5773502691896258f;    // 1/sqrt(3)

    const int E = cnt[0];
    const int ntile = (E + 31) >> 5;
    const int items = 3 * ntile;

    for (int item = blockIdx.x; item < items; item += gridDim.x) {
        const int conv = (item < ntile) ? 0 : ((item < 2 * ntile) ? 1 : 2);
        const int tile = item - conv * ntile;
        const int base = tile << 5;
        const u16* Bc = PW + conv * PW_STRIDE;
        const float* W1 = (conv == 0) ? W1_0 : ((conv == 1) ? W1_1 : W1_2);

        __syncthreads();                      // protect LDS reuse across items
        if (tid < 32) {
            int ge = base + tid;
            if (ge < E) {
                float4 v = edges[ge];
                metaL[tid] = __float_as_int(v.x);
                basL[tid][0] = v.y; basL[tid][1] = v.z; basL[tid][2] = v.w;
            } else {
                metaL[tid] = -1;
                basL[tid][0] = 0.0f; basL[tid][1] = 0.0f; basL[tid][2] = 0.0f;
            }
        }
        __syncthreads();

        // ---- layer 1 (scalar fp32, tiny K=3) -> XA (bf16), zero pads
        {
            int e = tid >> 3;
            int kb = (tid & 7) * 20;
            float b0 = basL[e][0], b1 = basL[e][1], b2 = basL[e][2];
            #pragma unroll 4
            for (int i = 0; i < 20; ++i) {
                int k = kb + i;
                float v = 0.0f;
                if (k < 150)
                    v = sp5(S1 * (b0 * W1[k] + b1 * W1[150 + k] + b2 * W1[300 + k]));
                XA[e * 168 + k] = f2bf(v);
            }
        }
        __syncthreads();

        mfma_layer(XA, XB, Bc, m_off, nh, lane);           // layer 2
        __syncthreads();
        mfma_layer(XB, XA, Bc + 25600, m_off, nh, lane);   // layer 3
        __syncthreads();

        // ---- output layer (no activation; 1/sqrt(150), 1/sqrt(din) folded)
        const u16* Bo = Bc + PW_OUT_OFF;
        if (conv == 0) {
            // TOUT=32: wave (m, nh) computes nt = nh
            bf16x8 a[5];
            load_a(a, XA, m_off, lane);
            f32x4 acc = mfma_nt(a, Bo, nh, lane);
            float* YF = (float*)XB;                         // 32 x 33 fp32
            #pragma unroll
            for (int r = 0; r < 4; ++r)
                YF[(m_off + quad * 4 + r) * 33 + nh * 16 + n_lane] = acc[r];
            __syncthreads();
            // fused scatter0: f1[a] += K.f0[n]; f1[n] += K.f0[a]
            int e = tid >> 3, i = tid & 7;
            int meta = metaL[e];
            if (meta >= 0) {
                int b = meta / NN;
                int rm = meta - b * NN;
                int aa = rm / NATOM;
                int nn2 = rm - aa * NATOM;
                const float* Kr = &YF[e * 33 + i * 4];
                const float* fn = f0 + (size_t)(b * NATOM + nn2) * 4;
                float d1 = Kr[0] * fn[0] + Kr[1] * fn[1] + Kr[2] * fn[2] + Kr[3] * fn[3];
                atomicAdd(&f1[(size_t)(b * NATOM + aa) * 8 + i], d1);
                if (nn2 != aa) {
                    const float* fa = f0 + (size_t)(b * NATOM + aa) * 4;
                    float d2 = Kr[0] * fa[0] + Kr[1] * fa[1] + Kr[2] * fa[2] + Kr[3] * fa[3];
                    atomicAdd(&f1[(size_t)(b * NATOM + nn2) * 8 + i], d2);
                }
            }
        } else {
            // TOUT=64: wave handles nt = nh*2, nh*2+1; K -> LDS bf16 -> bulk store
            bf16x8 a[5];
            load_a(a, XA, m_off, lane);
            u16* KB = XB;                                   // 32 x 64 bf16
            #pragma unroll
            for (int t2 = 0; t2 < 2; ++t2) {
                int nt = nh * 2 + t2;
                f32x4 acc = mfma_nt(a, Bo, nt, lane);
                #pragma unroll
                for (int r = 0; r < 4; ++r)
                    KB[(m_off + quad * 4 + r) * 64 + nt * 16 + n_lane] = f2bf(acc[r]);
            }
            __syncthreads();
            u16* Kc = (conv == 1) ? Kc1 : Kc2;
            *(uint4*)(Kc + (size_t)base * 64 + tid * 8) = *(const uint4*)(KB + tid * 8);
        }
    }
}

// ---------------- scatter (bf16 K, DIN=8): f_out[a]+=K.f[n]; f_out[n]+=K.f[a]
__global__ void scatter_bf16(const u16* __restrict__ Kc, const float* __restrict__ f_in,
                             float* __restrict__ f_out, const float4* __restrict__ edges,
                             const int* __restrict__ cnt) {
    const int E = cnt[0];
    const int total = E * 8;
    for (int idx = blockIdx.x * blockDim.x + threadIdx.x; idx < total;
         idx += gridDim.x * blockDim.x) {
        int e = idx >> 3, i = idx & 7;
        int meta = __float_as_int(edges[e].x);
        int b = meta / NN;
        int rm = meta - b * NN;
        int a = rm / NATOM;
        int n = rm - a * NATOM;
        float kr[8];
        const u16* kp = Kc + (size_t)e * 64 + i * 8;
        #pragma unroll
        for (int j = 0; j < 8; ++j) kr[j] = bf2f(kp[j]);
        const float* fn = f_in + (size_t)(b * NATOM + n) * 8;
        float d1 = 0.0f;
        #pragma unroll
        for (int j = 0; j < 8; ++j) d1 += kr[j] * fn[j];
        atomicAdd(&f_out[(size_t)(b * NATOM + a) * 8 + i], d1);
        if (n != a) {
            const float* fa = f_in + (size_t)(b * NATOM + a) * 8;
            float d2 = 0.0f;
            #pragma unroll
            for (int j = 0; j < 8; ++j) d2 += kr[j] * fa[j];
            atomicAdd(&f_out[(size_t)(b * NATOM + n) * 8 + i], d2);
        }
    }
}

// ---------------- epilogue: lp_pool + linear + BN(batch of 2) + LeakyReLU ---
__global__ void epilogue_kernel(const float* __restrict__ f1, const float* __restrict__ f2,
                                const float* __restrict__ f3,
                                const float* __restrict__ lin_w, const float* __restrict__ lin_b,
                                const float* __restrict__ bn_g, const float* __restrict__ bn_b,
                                float* __restrict__ out) {
    __shared__ float ps[240];
    __shared__ float pooled[48];
    __shared__ float yv[48];
    int tid = threadIdx.x;
    if (tid < 240) {
        int ch = tid % 48, seg = tid / 48;
        int b = ch / 24, cc = ch % 24;
        const float* src = (cc < 8)  ? (f1 + (size_t)(b * NATOM) * 8 + cc)
                         : (cc < 16) ? (f2 + (size_t)(b * NATOM) * 8 + (cc - 8))
                                     : (f3 + (size_t)(b * NATOM) * 8 + (cc - 16));
        int n0 = seg * 58, n1 = (286 < n0 + 58) ? 286 : (n0 + 58);
        float s = 0.0f;
        for (int n = n0; n < n1; ++n) { float v = src[(size_t)n * 8]; s += v * v; }
        ps[tid] = s;
    }
    __syncthreads();
    if (tid < 48)
        pooled[tid] = sqrtf(ps[tid] + ps[tid + 48] + ps[tid + 96] + ps[tid + 144]
                            + ps[tid + 192] + 1e-12f);
    __syncthreads();
    if (tid < 48) {
        int b = tid / 24, o = tid % 24;
        float y = lin_b[o];
        for (int cc = 0; cc < 24; ++cc) y += pooled[b * 24 + cc] * lin_w[o * 24 + cc];
        yv[b * 24 + o] = y;
    }
    __syncthreads();
    if (tid < 24) {
        int o = tid;
        float y0 = yv[o], y1 = yv[24 + o];
        float m = 0.5f * (y0 + y1);
        float v = 0.5f * ((y0 - m) * (y0 - m) + (y1 - m) * (y1 - m));
        float inv = rsqrtf(v + 1e-5f);
        float g = bn_g[o], bb = bn_b[o];
        float t0 = (y0 - m) * inv * g + bb;
        float t1 = (y1 - m) * inv * g + bb;
        out[o]      = t0 > 0.0f ? t0 : 0.2f * t0;
        out[24 + o] = t1 > 0.0f ? t1 : 0.2f * t1;
    }
}

extern "C" void kernel_launch(void* const* d_in, const int* in_sizes, int n_in,
                              void* d_out, int out_size, void* d_ws, size_t ws_size,
                              hipStream_t stream) {
    const float* xyz  = (const float*)d_in[0];
    const int*   Z    = (const int*)d_in[1];
    const float* emb  = (const float*)d_in[2];
    const float* c0w1 = (const float*)d_in[3];
    const float* c0w2 = (const float*)d_in[4];
    const float* c0w3 = (const float*)d_in[5];
    const float* c0wo = (const float*)d_in[6];
    const float* c1w1 = (const float*)d_in[7];
    const float* c1w2 = (const float*)d_in[8];
    const float* c1w3 = (const float*)d_in[9];
    const float* c1wo = (const float*)d_in[10];
    const float* c2w1 = (const float*)d_in[11];
    const float* c2w2 = (const float*)d_in[12];
    const float* c2w3 = (const float*)d_in[13];
    const float* c2wo = (const float*)d_in[14];
    const float* linw = (const float*)d_in[15];
    const float* linb = (const float*)d_in[16];
    const float* bng  = (const float*)d_in[17];
    const float* bnb  = (const float*)d_in[18];
    float* outp = (float*)d_out;

    // ws: [cnt][edges][f0][f1][f2][f3][PW bf16][Kc1][Kc2]  (~23 MB)
    char* ws = (char*)d_ws;
    int* cnt = (int*)ws;
    float4* edges = (float4*)(ws + 16);
    size_t off = 16 + (size_t)ECAP * 16;
    float* f0 = (float*)(ws + off); off += (size_t)NB2 * NATOM * 4 * 4;
    float* f1 = (float*)(ws + off); off += (size_t)NB2 * NATOM * 8 * 4;
    float* f2 = (float*)(ws + off); off += (size_t)NB2 * NATOM * 8 * 4;
    float* f3 = (float*)(ws + off); off += (size_t)NB2 * NATOM * 8 * 4;
    off = (off + 255) & ~(size_t)255;
    u16* PW = (u16*)(ws + off); off += (size_t)3 * PW_STRIDE * 2;
    off = (off + 255) & ~(size_t)255;
    u16* Kc1 = (u16*)(ws + off); off += (size_t)ECAP * 128;
    u16* Kc2 = (u16*)(ws + off);

    prep_kernel<<<128, 256, 0, stream>>>(Z, emb, c0w2, c0w3, c0wo,
                                         c1w2, c1w3, c1wo, c2w2, c2w3, c2wo,
                                         f0, f1, cnt, PW);
    edge_kernel<<<(NB2 * NN + 255) / 256, 256, 0, stream>>>(xyz, edges, cnt);
    radial_kernel<<<640, 256, 0, stream>>>(c0w1, c1w1, c2w1, PW, f0, f1,
                                           Kc1, Kc2, edges, cnt);
    scatter_bf16<<<128, 256, 0, stream>>>(Kc1, f1, f2, edges, cnt);
    scatter_bf16<<<128, 256, 0, stream>>>(Kc2, f2, f3, edges, cnt);
    epilogue_kernel<<<1, 256, 0, stream>>>(f1, f2, f3, linw, linb, bng, bnb, outp);
}

// Round 4
// 152.336 us; speedup vs baseline: 2.8367x; 1.0616x over previous
//
#include <hip/hip_runtime.h>
#include <math.h>

#define NATOM 286
#define NB2   2
#define NN    81796          /* 286*286 */
#define ECAP  82082          /* 2 * 286*287/2 : max unordered pairs incl. self */
#define PW_STRIDE 61440      /* u16 per conv: W2 25600 + W3 25600 + Wo 10240 */
#define PW_OUT_OFF 51200

typedef unsigned short u16;
typedef unsigned int   u32;

using bf16x8 = __attribute__((ext_vector_type(8))) short;
using f32x4  = __attribute__((ext_vector_type(4))) float;

// Softplus(beta=5), stable: (max(z,0) + log(1+exp(-|z|)))/5
__device__ __forceinline__ float sp5(float x) {
    float z = 5.0f * x;
    return (fmaxf(z, 0.0f) + __logf(1.0f + __expf(-fabsf(z)))) * 0.2f;
}
__device__ __forceinline__ u16 f2bf(float x) {           // RTNE fp32->bf16
    union { float f; u32 u; } v; v.f = x;
    return (u16)((v.u + 0x7FFFu + ((v.u >> 16) & 1u)) >> 16);
}
__device__ __forceinline__ float bf2f(u16 u) {
    union { u32 u; float f; } v; v.u = ((u32)u) << 16;
    return v.f;
}

// ---------------- prep: cnt=0, f0=emb[Z], zero f1..f3, pack weights --------
// Packed B-fragment layout (per 16x16x32 mfma): dst[((nt*5+k0)*64+lane)*8+j]
//   = W[k = k0*32 + (lane>>4)*8 + j][n = nt*16 + (lane&15)] * scale  (0 pad)
__global__ void prep_kernel(const int* __restrict__ Z, const float* __restrict__ emb,
                            const float* w2a, const float* w3a, const float* woa,
                            const float* w2b, const float* w3b, const float* wob,
                            const float* w2c, const float* w3c, const float* woc,
                            float* __restrict__ f0, float* __restrict__ f123,
                            int* __restrict__ cnt, u16* __restrict__ PW) {
    int idx = blockIdx.x * blockDim.x + threadIdx.x;
    int stride = gridDim.x * blockDim.x;
    if (idx == 0) cnt[0] = 0;
    for (int i = idx; i < NB2 * NATOM * 4; i += stride)
        f0[i] = emb[Z[i >> 2] * 4 + (i & 3)];
    for (int i = idx; i < NB2 * NATOM * 8 * 3; i += stride)
        f123[i] = 0.0f;

    const float SH = 0.08164965809277261f;   // 1/sqrt(150)
    const float* W2s[3] = {w2a, w2b, w2c};
    const float* W3s[3] = {w3a, w3b, w3c};
    const float* Wos[3] = {woa, wob, woc};
    const int   TOUTs[3] = {32, 64, 64};
    const float SDs[3]  = {0.5f, 0.3535533905932738f, 0.3535533905932738f};

    for (int c = 0; c < 3; ++c) {
        u16* base = PW + c * PW_STRIDE;
        for (int which = 0; which < 2; ++which) {       // W2, W3 (150x150)
            const float* src = which ? W3s[c] : W2s[c];
            u16* dst = base + which * 25600;
            for (int d = idx; d < 25600; d += stride) {
                int j = d & 7, lane = (d >> 3) & 63, rest = d >> 9;
                int k0 = rest % 5, nt = rest / 5;
                int n = nt * 16 + (lane & 15);
                int k = k0 * 32 + (lane >> 4) * 8 + j;
                float v = (k < 150 && n < 150) ? src[k * 150 + n] * SH : 0.0f;
                dst[d] = f2bf(v);
            }
        }
        const float* src = Wos[c];                      // Wo (150 x TOUT)
        const int TOUT = TOUTs[c];
        const float sc = SH * SDs[c];                   // fold 1/sqrt(d_in) too
        u16* dst = base + PW_OUT_OFF;
        const int tot = (TOUT / 16) * 5 * 512;
        for (int d = idx; d < tot; d += stride) {
            int j = d & 7, lane = (d >> 3) & 63, rest = d >> 9;
            int k0 = rest % 5, nt = rest / 5;
            int n = nt * 16 + (lane & 15);
            int k = k0 * 32 + (lane >> 4) * 8 + j;
            float v = (k < 150) ? src[k * TOUT + n] * sc : 0.0f;
            dst[d] = f2bf(v);
        }
    }
}

// ---------------- edge compaction: unordered pairs (a<=n) with dist<=3 ------
// Ballot-compacted: ONE global atomic per block (vs per-wave) to kill the
// same-address L2 atomic serialization on cnt.
__global__ void edge_kernel(const float* __restrict__ xyz, float4* __restrict__ edges,
                            int* __restrict__ cnt) {
    int tid = threadIdx.x;
    int idx = blockIdx.x * blockDim.x + tid;
    int lane = tid & 63, wv = tid >> 6;
    bool hit = false;
    float b0 = 0.0f, b1 = 0.0f, b2 = 0.0f;
    int meta = -1;
    if (idx < NB2 * NN) {
        int b = idx / NN;
        int rem = idx - b * NN;
        int a = rem / NATOM;
        int n = rem - a * NATOM;
        if (n >= a) {
            const float* pa = xyz + (size_t)(b * NATOM + a) * 3;
            const float* pn = xyz + (size_t)(b * NATOM + n) * 3;
            float dx = pa[0] - pn[0];
            float dy = pa[1] - pn[1];
            float dz = pa[2] - pn[2];
            float d = sqrtf(dx * dx + dy * dy + dz * dz + 1e-12f);
            if (d <= 3.0f) {
                hit = true;
                meta = idx;
                float bas[3];
                #pragma unroll
                for (int k = 0; k < 3; ++k) {
                    float x = (d - 1.5f * (float)k) * (1.0f / 1.5f);
                    float v = 0.0f;
                    if (fabsf(x) < 1.0f) {
                        float ct = cosf(1.5707963267948966f * x);
                        v = ct * ct;
                    }
                    bas[k] = v;
                }
                b0 = bas[0]; b1 = bas[1]; b2 = bas[2];
            }
        }
    }
    unsigned long long m = __ballot(hit);
    int nw = __popcll(m);
    int before = __popcll(m & ((1ull << lane) - 1ull));
    __shared__ int wb[4];
    __shared__ int gb;
    if (lane == 0) wb[wv] = nw;
    __syncthreads();
    if (tid == 0) gb = atomicAdd(cnt, wb[0] + wb[1] + wb[2] + wb[3]);
    __syncthreads();
    int base = gb + before;
    for (int w = 0; w < wv; ++w) base += wb[w];
    if (hit) edges[base] = make_float4(__int_as_float(meta), b0, b1, b2);
}

// ---------------- MFMA helpers ---------------------------------------------
// A frag (X[m][k], row stride 168 u16): lane holds X[m=lane&15][k0*32+(lane>>4)*8+j]
__device__ __forceinline__ void load_a(bf16x8 a[5], const u16* X, int m_off, int lane) {
    const int arow = (m_off + (lane & 15)) * 168 + (lane >> 4) * 8;
    #pragma unroll
    for (int k0 = 0; k0 < 5; ++k0)
        a[k0] = *(const bf16x8*)(X + arow + k0 * 32);
}
__device__ __forceinline__ f32x4 mfma_nt(const bf16x8 a[5], const u16* __restrict__ Bp,
                                         int nt, int lane) {
    f32x4 acc = {0.0f, 0.0f, 0.0f, 0.0f};
    #pragma unroll
    for (int k0 = 0; k0 < 5; ++k0) {
        bf16x8 b = *(const bf16x8*)(Bp + ((nt * 5 + k0) * 64 + lane) * 8);
        acc = __builtin_amdgcn_mfma_f32_16x16x32_bf16(a[k0], b, acc, 0, 0, 0);
    }
    return acc;
}
// one hidden layer: Y = sp5(X @ Wp)   (scale folded into Wp)
__device__ __forceinline__ void mfma_layer(const u16* X, u16* Y,
                                           const u16* __restrict__ Bp,
                                           int m_off, int nh, int lane) {
    bf16x8 a[5];
    load_a(a, X, m_off, lane);
    const int quad = lane >> 4;
    const int n_lane = lane & 15;
    #pragma unroll
    for (int i = 0; i < 5; ++i) {
        int nt = nh * 5 + i;
        f32x4 acc = mfma_nt(a, Bp, nt, lane);
        // C/D: col = lane&15, row = quad*4 + r   [measured m89/m91]
        int wb = (m_off + quad * 4) * 168 + nt * 16 + n_lane;
        #pragma unroll
        for (int r = 0; r < 4; ++r)
            Y[wb + r * 168] = f2bf(sp5(acc[r]));
    }
}

// ---------------- radial MLP (MFMA) for all 3 convs + fused conv0 scatter ---
// 32-edge tiles; 256 threads = 4 waves = (m-half 0/1) x (n-half 0/1).
// Grid 1024: 1 item per block for any realistic E; 4 blocks/CU resident.
__global__ __launch_bounds__(256, 4)
void radial_kernel(const float* __restrict__ W1_0, const float* __restrict__ W1_1,
                   const float* __restrict__ W1_2, const u16* __restrict__ PW,
                   const float* __restrict__ f0, float* __restrict__ f1,
                   u16* __restrict__ Kc1, u16* __restrict__ Kc2,
                   const float4* __restrict__ edges, const int* __restrict__ cnt) {
    __shared__ __align__(16) u16 XA[32 * 168];
    __shared__ __align__(16) u16 XB[32 * 168];
    __shared__ float basL[32][3];
    __shared__ int metaL[32];

    const int tid = threadIdx.x;
    const int lane = tid & 63;
    const int wv = tid >> 6;
    const int m_off = (wv & 1) * 16;
    const int nh = wv >> 1;
    const int n_lane = lane & 15;
    const int quad = lane >> 4;
    const float S1 = 0.5773502691896258f;    // 1/sqrt(3)

    const int E = cnt[0];
    const int ntile = (E + 31) >> 5;
    const int items = 3 * ntile;

    for (int item = blockIdx.x; item < items; item += gridDim.x) {
        const int conv = (item < ntile) ? 0 : ((item < 2 * ntile) ? 1 : 2);
        const int tile = item - conv * ntile;
        const int base = tile << 5;
        const u16* Bc = PW + conv * PW_STRIDE;
        const float* W1 = (conv == 0) ? W1_0 : ((conv == 1) ? W1_1 : W1_2);

        __syncthreads();                      // protect LDS reuse across items
        if (tid < 32) {
            int ge = base + tid;
            if (ge < E) {
                float4 v = edges[ge];
                metaL[tid] = __float_as_int(v.x);
                basL[tid][0] = v.y; basL[tid][1] = v.z; basL[tid][2] = v.w;
            } else {
                metaL[tid] = -1;
                basL[tid][0] = 0.0f; basL[tid][1] = 0.0f; basL[tid][2] = 0.0f;
            }
        }
        __syncthreads();

        // ---- layer 1 (scalar fp32, tiny K=3) -> XA (bf16), zero pads
        {
            int e = tid >> 3;
            int kb = (tid & 7) * 20;
            float b0 = basL[e][0], b1 = basL[e][1], b2 = basL[e][2];
            #pragma unroll 4
            for (int i = 0; i < 20; ++i) {
                int k = kb + i;
                float v = 0.0f;
                if (k < 150)
                    v = sp5(S1 * (b0 * W1[k] + b1 * W1[150 + k] + b2 * W1[300 + k]));
                XA[e * 168 + k] = f2bf(v);
            }
        }
        __syncthreads();

        mfma_layer(XA, XB, Bc, m_off, nh, lane);           // layer 2
        __syncthreads();
        mfma_layer(XB, XA, Bc + 25600, m_off, nh, lane);   // layer 3
        __syncthreads();

        // ---- output layer (no activation; 1/sqrt(150), 1/sqrt(din) folded)
        const u16* Bo = Bc + PW_OUT_OFF;
        if (conv == 0) {
            // TOUT=32: wave (m, nh) computes nt = nh
            bf16x8 a[5];
            load_a(a, XA, m_off, lane);
            f32x4 acc = mfma_nt(a, Bo, nh, lane);
            float* YF = (float*)XB;                         // 32 x 33 fp32
            #pragma unroll
            for (int r = 0; r < 4; ++r)
                YF[(m_off + quad * 4 + r) * 33 + nh * 16 + n_lane] = acc[r];
            __syncthreads();
            // fused scatter0: f1[a] += K.f0[n]; f1[n] += K.f0[a]
            int e = tid >> 3, i = tid & 7;
            int meta = metaL[e];
            if (meta >= 0) {
                int b = meta / NN;
                int rm = meta - b * NN;
                int aa = rm / NATOM;
                int nn2 = rm - aa * NATOM;
                const float* Kr = &YF[e * 33 + i * 4];
                const float* fn = f0 + (size_t)(b * NATOM + nn2) * 4;
                float d1 = Kr[0] * fn[0] + Kr[1] * fn[1] + Kr[2] * fn[2] + Kr[3] * fn[3];
                atomicAdd(&f1[(size_t)(b * NATOM + aa) * 8 + i], d1);
                if (nn2 != aa) {
                    const float* fa = f0 + (size_t)(b * NATOM + aa) * 4;
                    float d2 = Kr[0] * fa[0] + Kr[1] * fa[1] + Kr[2] * fa[2] + Kr[3] * fa[3];
                    atomicAdd(&f1[(size_t)(b * NATOM + nn2) * 8 + i], d2);
                }
            }
        } else {
            // TOUT=64: wave handles nt = nh*2, nh*2+1; K -> LDS bf16 -> bulk store
            bf16x8 a[5];
            load_a(a, XA, m_off, lane);
            u16* KB = XB;                                   // 32 x 64 bf16
            #pragma unroll
            for (int t2 = 0; t2 < 2; ++t2) {
                int nt = nh * 2 + t2;
                f32x4 acc = mfma_nt(a, Bo, nt, lane);
                #pragma unroll
                for (int r = 0; r < 4; ++r)
                    KB[(m_off + quad * 4 + r) * 64 + nt * 16 + n_lane] = f2bf(acc[r]);
            }
            __syncthreads();
            u16* Kc = (conv == 1) ? Kc1 : Kc2;
            *(uint4*)(Kc + (size_t)base * 64 + tid * 8) = *(const uint4*)(KB + tid * 8);
        }
    }
}

// ---------------- scatter (bf16 K, DIN=8): f_out[a]+=K.f[n]; f_out[n]+=K.f[a]
__global__ void scatter_bf16(const u16* __restrict__ Kc, const float* __restrict__ f_in,
                             float* __restrict__ f_out, const float4* __restrict__ edges,
                             const int* __restrict__ cnt) {
    const int E = cnt[0];
    const int total = E * 8;
    for (int idx = blockIdx.x * blockDim.x + threadIdx.x; idx < total;
         idx += gridDim.x * blockDim.x) {
        int e = idx >> 3, i = idx & 7;
        int meta = __float_as_int(edges[e].x);
        int b = meta / NN;
        int rm = meta - b * NN;
        int a = rm / NATOM;
        int n = rm - a * NATOM;
        float kr[8];
        const u16* kp = Kc + (size_t)e * 64 + i * 8;
        #pragma unroll
        for (int j = 0; j < 8; ++j) kr[j] = bf2f(kp[j]);
        const float* fn = f_in + (size_t)(b * NATOM + n) * 8;
        float d1 = 0.0f;
        #pragma unroll
        for (int j = 0; j < 8; ++j) d1 += kr[j] * fn[j];
        atomicAdd(&f_out[(size_t)(b * NATOM + a) * 8 + i], d1);
        if (n != a) {
            const float* fa = f_in + (size_t)(b * NATOM + a) * 8;
            float d2 = 0.0f;
            #pragma unroll
            for (int j = 0; j < 8; ++j) d2 += kr[j] * fa[j];
            atomicAdd(&f_out[(size_t)(b * NATOM + n) * 8 + i], d2);
        }
    }
}

// ---------------- epilogue: lp_pool + linear + BN(batch of 2) + LeakyReLU ---
__global__ void epilogue_kernel(const float* __restrict__ f1, const float* __restrict__ f2,
                                const float* __restrict__ f3,
                                const float* __restrict__ lin_w, const float* __restrict__ lin_b,
                                const float* __restrict__ bn_g, const float* __restrict__ bn_b,
                                float* __restrict__ out) {
    __shared__ float ps[240];
    __shared__ float pooled[48];
    __shared__ float yv[48];
    int tid = threadIdx.x;
    if (tid < 240) {
        int ch = tid % 48, seg = tid / 48;
        int b = ch / 24, cc = ch % 24;
        const float* src = (cc < 8)  ? (f1 + (size_t)(b * NATOM) * 8 + cc)
                         : (cc < 16) ? (f2 + (size_t)(b * NATOM) * 8 + (cc - 8))
                                     : (f3 + (size_t)(b * NATOM) * 8 + (cc - 16));
        int n0 = seg * 58, n1 = (286 < n0 + 58) ? 286 : (n0 + 58);
        float s = 0.0f;
        for (int n = n0; n < n1; ++n) { float v = src[(size_t)n * 8]; s += v * v; }
        ps[tid] = s;
    }
    __syncthreads();
    if (tid < 48)
        pooled[tid] = sqrtf(ps[tid] + ps[tid + 48] + ps[tid + 96] + ps[tid + 144]
                            + ps[tid + 192] + 1e-12f);
    __syncthreads();
    if (tid < 48) {
        int b = tid / 24, o = tid % 24;
        float y = lin_b[o];
        for (int cc = 0; cc < 24; ++cc) y += pooled[b * 24 + cc] * lin_w[o * 24 + cc];
        yv[b * 24 + o] = y;
    }
    __syncthreads();
    if (tid < 24) {
        int o = tid;
        float y0 = yv[o], y1 = yv[24 + o];
        float m = 0.5f * (y0 + y1);
        float v = 0.5f * ((y0 - m) * (y0 - m) + (y1 - m) * (y1 - m));
        float inv = rsqrtf(v + 1e-5f);
        float g = bn_g[o], bb = bn_b[o];
        float t0 = (y0 - m) * inv * g + bb;
        float t1 = (y1 - m) * inv * g + bb;
        out[o]      = t0 > 0.0f ? t0 : 0.2f * t0;
        out[24 + o] = t1 > 0.0f ? t1 : 0.2f * t1;
    }
}

extern "C" void kernel_launch(void* const* d_in, const int* in_sizes, int n_in,
                              void* d_out, int out_size, void* d_ws, size_t ws_size,
                              hipStream_t stream) {
    const float* xyz  = (const float*)d_in[0];
    const int*   Z    = (const int*)d_in[1];
    const float* emb  = (const float*)d_in[2];
    const float* c0w1 = (const float*)d_in[3];
    const float* c0w2 = (const float*)d_in[4];
    const float* c0w3 = (const float*)d_in[5];
    const float* c0wo = (const float*)d_in[6];
    const float* c1w1 = (const float*)d_in[7];
    const float* c1w2 = (const float*)d_in[8];
    const float* c1w3 = (const float*)d_in[9];
    const float* c1wo = (const float*)d_in[10];
    const float* c2w1 = (const float*)d_in[11];
    const float* c2w2 = (const float*)d_in[12];
    const float* c2w3 = (const float*)d_in[13];
    const float* c2wo = (const float*)d_in[14];
    const float* linw = (const float*)d_in[15];
    const float* linb = (const float*)d_in[16];
    const float* bng  = (const float*)d_in[17];
    const float* bnb  = (const float*)d_in[18];
    float* outp = (float*)d_out;

    // ws: [cnt][edges][f0][f1][f2][f3][PW bf16][Kc1][Kc2]  (~23 MB)
    char* ws = (char*)d_ws;
    int* cnt = (int*)ws;
    float4* edges = (float4*)(ws + 16);
    size_t off = 16 + (size_t)ECAP * 16;
    float* f0 = (float*)(ws + off); off += (size_t)NB2 * NATOM * 4 * 4;
    float* f1 = (float*)(ws + off); off += (size_t)NB2 * NATOM * 8 * 4;
    float* f2 = (float*)(ws + off); off += (size_t)NB2 * NATOM * 8 * 4;
    float* f3 = (float*)(ws + off); off += (size_t)NB2 * NATOM * 8 * 4;
    off = (off + 255) & ~(size_t)255;
    u16* PW = (u16*)(ws + off); off += (size_t)3 * PW_STRIDE * 2;
    off = (off + 255) & ~(size_t)255;
    u16* Kc1 = (u16*)(ws + off); off += (size_t)ECAP * 128;
    u16* Kc2 = (u16*)(ws + off);

    prep_kernel<<<128, 256, 0, stream>>>(Z, emb, c0w2, c0w3, c0wo,
                                         c1w2, c1w3, c1wo, c2w2, c2w3, c2wo,
                                         f0, f1, cnt, PW);
    edge_kernel<<<(NB2 * NN + 255) / 256, 256, 0, stream>>>(xyz, edges, cnt);
    radial_kernel<<<1024, 256, 0, stream>>>(c0w1, c1w1, c2w1, PW, f0, f1,
                                            Kc1, Kc2, edges, cnt);
    scatter_bf16<<<256, 256, 0, stream>>>(Kc1, f1, f2, edges, cnt);
    scatter_bf16<<<256, 256, 0, stream>>>(Kc2, f2, f3, edges, cnt);
    epilogue_kernel<<<1, 256, 0, stream>>>(f1, f2, f3, linw, linb, bng, bnb, outp);
}